// Round 6
// baseline (736.006 us; speedup 1.0000x reference)
//
#include <hip/hip_runtime.h>
#include <hip/hip_bf16.h>
#include <math.h>

#define H     1024
#define FFN   4096
#define NE    8
#define TOK   2048
#define PAIRS (TOK*2)
#define BM    128
#define BK    32
#define ROWCAP (PAIRS + NE*BM)   /* 5120 worst-case padded rows */
#define MAXTILES (ROWCAP/BM)     /* 40 */

typedef unsigned short u16;
typedef __attribute__((ext_vector_type(8))) __bf16 bf16x8;
typedef __attribute__((ext_vector_type(4))) float  f32x4;

// hardware v_cvt_pk_bf16_f32: 2 floats -> packed 2xbf16 in one inst
__device__ __forceinline__ unsigned cvt2(float a, float b) {
    __hip_bfloat162 h = __float22bfloat162_rn(float2{a, b});
    unsigned u;
    __builtin_memcpy(&u, &h, 4);
    return u;
}

#define GLD16(gp, lp) __builtin_amdgcn_global_load_lds( \
    (const __attribute__((address_space(1))) void*)(gp), \
    (__attribute__((address_space(3))) void*)(lp), 16, 0, 0)

// Swizzle convention (everywhere): a bf16 row of K-contiguous data stores
// 16B-slot s at s ^ ((row>>1)&3) within each 4-slot (32-elem) group; the
// ds_read side XORs identically (aslot = quad ^ ((m16>>1)&3)). Verified in
// r2/r5 on xg and act. Now also applied to w13b/w2b by the cvt kernels, so
// ALL GEMM operands stage via global_load_lds with conflict-free reads.

// ---------------- kernel 1: init counts ----------------
__global__ void k_init(int* counts) {
    if (threadIdx.x < NE) counts[threadIdx.x] = 0;
}

// ---------------- weights fp32 -> bf16 (pre-swizzled), pure BW ----------------
// w13: [E*2F rows][H]; 4 rows per block, 1 float4/thread/row.
__global__ void k_cvt13(const float4* __restrict__ w4, u16* __restrict__ wb) {
    int t = threadIdx.x;
#pragma unroll
    for (int i = 0; i < 4; i++) {
        int r = blockIdx.x * 4 + i;
        int f2 = ((r >> 1) & 3) << 1;
        float4 v = w4[(size_t)r * (H / 4) + t];
        uint2 o = { cvt2(v.x, v.y), cvt2(v.z, v.w) };
        *(uint2*)&wb[(size_t)r * H + ((t ^ f2) << 2)] = o;
    }
}
// w2: [E*H rows][FFN]; 1 row per block, 4 float4/thread.
__global__ void k_cvt2(const float4* __restrict__ w4, u16* __restrict__ wb) {
    int r = blockIdx.x;
    int f2 = ((r >> 1) & 3) << 1;
#pragma unroll
    for (int i = 0; i < 4; i++) {
        int f = threadIdx.x + i * 256;
        float4 v = w4[(size_t)r * (FFN / 4) + f];
        uint2 o = { cvt2(v.x, v.y), cvt2(v.z, v.w) };
        *(uint2*)&wb[(size_t)r * FFN + ((f ^ f2) << 2)] = o;
    }
}

// ---------------- kernel 2: router ----------------
__global__ void k_router(const float* __restrict__ x, const float* __restrict__ gw,
                         float* __restrict__ logits, int* counts,
                         int* __restrict__ sel, int* __restrict__ posn, float* __restrict__ wgt) {
    int lane = threadIdx.x & 63;
    int t = blockIdx.x * 4 + (threadIdx.x >> 6);
    float p[NE];
#pragma unroll
    for (int e = 0; e < NE; e++) p[e] = 0.f;
    for (int j = 0; j < H / 64; j++) {
        int h = lane + j * 64;
        float xv = x[(size_t)t * H + h];
#pragma unroll
        for (int e = 0; e < NE; e++) p[e] = fmaf(xv, gw[e * H + h], p[e]);
    }
#pragma unroll
    for (int off = 32; off; off >>= 1)
#pragma unroll
        for (int e = 0; e < NE; e++) p[e] += __shfl_xor(p[e], off, 64);
    if (lane == 0) {
        float mx = p[0];
#pragma unroll
        for (int e = 1; e < NE; e++) mx = fmaxf(mx, p[e]);
        float pe[NE];
#pragma unroll
        for (int e = 0; e < NE; e++) pe[e] = __expf(p[e] - mx);
        int i0 = 0;
#pragma unroll
        for (int e = 1; e < NE; e++) if (pe[e] > pe[i0]) i0 = e;
        int i1 = (i0 == 0) ? 1 : 0;
#pragma unroll
        for (int e = 0; e < NE; e++) if (e != i1 && e != i0 && pe[e] > pe[i1]) i1 = e;
        float w0 = pe[i0] / (pe[i0] + pe[i1]);
#pragma unroll
        for (int e = 0; e < NE; e++) logits[(size_t)t * NE + e] = p[e];
        int p0 = atomicAdd(&counts[i0], 1);
        int p1 = atomicAdd(&counts[i1], 1);
        sel[2 * t] = i0;  posn[2 * t] = p0;  wgt[2 * t] = w0;
        sel[2 * t + 1] = i1;  posn[2 * t + 1] = p1;  wgt[2 * t + 1] = 1.f - w0;
    }
}

// ---------------- kernel 3: prefix / tile map (one wave, parallel) ----------------
__global__ void k_prefix(const int* __restrict__ counts, int* __restrict__ base,
                         int* __restrict__ tile_e) {
    int lane = threadIdx.x;  // 64
    int cnt = (lane < NE) ? counts[lane] : 0;
    int nt = (cnt + BM - 1) / BM;
    int ntv[NE], tbv[NE];
    int b = 0, tb = 0;
#pragma unroll
    for (int e = 0; e < NE; e++) {
        int ne = __shfl(nt, e, 64);
        ntv[e] = ne; tbv[e] = tb;
        if (lane == e) base[e] = b;
        tb += ne; b += ne * BM;
    }
    if (lane == 0) base[NE] = b;
    if (lane < MAXTILES) {
        int e = -1;
#pragma unroll
        for (int k = 0; k < NE; k++)
            if (lane >= tbv[k] && lane < tbv[k] + ntv[k]) e = k;
        tile_e[lane] = e;
    }
}

// ---------------- kernel 4: gather x -> bf16 compacted rows (PRE-SWIZZLED) ----------------
__global__ void k_gather(const float4* __restrict__ x4, const int* __restrict__ sel,
                         const int* __restrict__ posn, const int* __restrict__ base,
                         u16* __restrict__ xg) {
    int p = blockIdx.x;
    int lane = threadIdx.x;       // 64 threads
    int t = p >> 1;
    int row = base[sel[p]] + posn[p];
    int f2 = ((row >> 1) & 3) << 1;
#pragma unroll
    for (int i = 0; i < 4; i++) {
        int idx = i * 64 + lane;
        float4 v = x4[(size_t)t * (H / 4) + (idx ^ f2)];
        uint2 o = { cvt2(v.x, v.y), cvt2(v.z, v.w) };
        *(uint2*)&xg[(size_t)row * H + idx * 4] = o;
    }
}

// ---------------- kernel 5 (bf16 weights): GEMM1 ----------------
// m97 structure: all operands via global_load_lds, double-buffered, single
// syncthreads per K-step (drains this wave's DMA -> cross-wave publish safe).
__global__ __launch_bounds__(256) void k_gemm1b(const u16* __restrict__ xg,
                                                const u16* __restrict__ w13b,
                                                u16* __restrict__ act,
                                                const int* __restrict__ tile_e) {
    int id = blockIdx.x;
    int xcd = id & 7;
    int j = id >> 3;
    int tile = j % MAXTILES;
    int n0i = xcd * 8 + j / MAXTILES;
    int e = tile_e[tile];
    if (e < 0) return;
    __shared__ u16 As[2][BM * BK];    // 2 x 8KB
    __shared__ u16 B1s[2][64 * BK];   // 2 x 4KB
    __shared__ u16 B3s[2][64 * BK];   // 2 x 4KB   -> 32KB total, 5 blocks/CU

    int tid = threadIdx.x;
    int lane = tid & 63, wave = tid >> 6;
    int quad = lane >> 4, m16 = lane & 15;
    int wm = wave >> 1, wn = wave & 1;
    int row0 = tile * BM;
    int n0 = n0i * 64;
    const u16* wb1 = w13b + ((size_t)e * 2 * FFN + n0) * H;
    const u16* wb3 = w13b + ((size_t)e * 2 * FFN + FFN + n0) * H;

    f32x4 accg[4][2], accu[4][2];
#pragma unroll
    for (int mi = 0; mi < 4; mi++)
#pragma unroll
        for (int ni = 0; ni < 2; ni++) { accg[mi][ni] = {0.f,0.f,0.f,0.f}; accu[mi][ni] = {0.f,0.f,0.f,0.f}; }

    int aslot = quad ^ ((m16 >> 1) & 3);
    const int NT = H / BK;   // 32

#define G1_STAGE(KK, BUF) {                                                              \
        _Pragma("unroll")                                                                \
        for (int i = 0; i < 2; i++) {                                                    \
            int c = i * 256 + tid;                                                       \
            GLD16(xg + (size_t)(row0 + (c >> 2)) * H + (KK) + (c & 3) * 8, As[BUF] + c * 8); \
        }                                                                                \
        GLD16(wb1 + (size_t)(tid >> 2) * H + (KK) + (tid & 3) * 8, B1s[BUF] + tid * 8);  \
        GLD16(wb3 + (size_t)(tid >> 2) * H + (KK) + (tid & 3) * 8, B3s[BUF] + tid * 8);  \
    }

    G1_STAGE(0, 0);
    __syncthreads();
    for (int it = 0; it < NT; ++it) {
        int cur = it & 1;
        if (it + 1 < NT) G1_STAGE((it + 1) * BK, cur ^ 1);
        bf16x8 a[4], bg[2], bu[2];
#pragma unroll
        for (int mi = 0; mi < 4; mi++)
            a[mi] = *(const bf16x8*)&As[cur][(wm * 64 + mi * 16 + m16) * BK + aslot * 8];
#pragma unroll
        for (int ni = 0; ni < 2; ni++) {
            bg[ni] = *(const bf16x8*)&B1s[cur][(wn * 32 + ni * 16 + m16) * BK + aslot * 8];
            bu[ni] = *(const bf16x8*)&B3s[cur][(wn * 32 + ni * 16 + m16) * BK + aslot * 8];
        }
#pragma unroll
        for (int mi = 0; mi < 4; mi++)
#pragma unroll
            for (int ni = 0; ni < 2; ni++) {
                accg[mi][ni] = __builtin_amdgcn_mfma_f32_16x16x32_bf16(a[mi], bg[ni], accg[mi][ni], 0, 0, 0);
                accu[mi][ni] = __builtin_amdgcn_mfma_f32_16x16x32_bf16(a[mi], bu[ni], accu[mi][ni], 0, 0, 0);
            }
        __syncthreads();
    }
#undef G1_STAGE

    // epilogue: silu(g)*u -> bf16 act, PRE-SWIZZLED for gemm2's A staging
#pragma unroll
    for (int mi = 0; mi < 4; mi++)
#pragma unroll
        for (int ni = 0; ni < 2; ni++) {
            int gcol = n0 + wn * 32 + ni * 16 + m16;
            int grow = row0 + wm * 64 + mi * 16 + quad * 4;
#pragma unroll
            for (int r = 0; r < 4; r++) {
                float g = accg[mi][ni][r], u = accu[mi][ni][r];
                float hv = g * (1.f / (1.f + __expf(-g))) * u;
                int f = ((quad * 4 + r) >> 1) & 3;
                act[(size_t)(grow + r) * FFN + (gcol ^ (f << 3))] = (u16)(cvt2(hv, hv) & 0xffff);
            }
        }
}

// ---------------- kernel 6 (bf16 weights): GEMM2, split-K = 2 ----------------
__global__ __launch_bounds__(256) void k_gemm2b(const u16* __restrict__ act,
                                                const u16* __restrict__ w2b,
                                                float* __restrict__ yc,
                                                const int* __restrict__ tile_e) {
    int id = blockIdx.x;
    int xcd = id & 7;
    int j = id >> 3;
    int tile = j % MAXTILES;
    int pz = xcd * 2 + j / MAXTILES;
    int e = tile_e[tile];
    if (e < 0) return;
    __shared__ u16 As[2][BM * BK];    // 2 x 8KB
    __shared__ u16 Bs[2][BM * BK];    // 2 x 8KB  -> 32KB total

    int tid = threadIdx.x;
    int lane = tid & 63, wave = tid >> 6;
    int quad = lane >> 4, m16 = lane & 15;
    int wm = wave >> 1, wn = wave & 1;
    int row0 = tile * BM;
    int n0 = (pz >> 1) * 128;
    int z = pz & 1;
    int k0 = z * (FFN / 2);
    const u16* wb = w2b + ((size_t)e * H + n0) * FFN;
    float* ycp = yc + (size_t)z * ROWCAP * H;

    f32x4 acc[4][4];
#pragma unroll
    for (int mi = 0; mi < 4; mi++)
#pragma unroll
        for (int ni = 0; ni < 4; ni++) acc[mi][ni] = {0.f,0.f,0.f,0.f};

    int aslot = quad ^ ((m16 >> 1) & 3);
    const int NT = (FFN / 2) / BK;   // 64

#define G2_STAGE(KK, BUF) {                                                               \
        _Pragma("unroll")                                                                 \
        for (int i = 0; i < 2; i++) {                                                     \
            int c = i * 256 + tid;                                                        \
            GLD16(act + (size_t)(row0 + (c >> 2)) * FFN + (KK) + (c & 3) * 8, As[BUF] + c * 8); \
        }                                                                                 \
        _Pragma("unroll")                                                                 \
        for (int i = 0; i < 2; i++) {                                                     \
            int c = i * 256 + tid;                                                        \
            GLD16(wb + (size_t)(c >> 2) * FFN + (KK) + (c & 3) * 8, Bs[BUF] + c * 8);     \
        }                                                                                 \
    }

    G2_STAGE(k0, 0);
    __syncthreads();
    for (int it = 0; it < NT; ++it) {
        int cur = it & 1;
        if (it + 1 < NT) G2_STAGE(k0 + (it + 1) * BK, cur ^ 1);
        bf16x8 a[4], b[4];
#pragma unroll
        for (int mi = 0; mi < 4; mi++)
            a[mi] = *(const bf16x8*)&As[cur][(wm * 64 + mi * 16 + m16) * BK + aslot * 8];
#pragma unroll
        for (int ni = 0; ni < 4; ni++)
            b[ni] = *(const bf16x8*)&Bs[cur][(wn * 64 + ni * 16 + m16) * BK + aslot * 8];
#pragma unroll
        for (int mi = 0; mi < 4; mi++)
#pragma unroll
            for (int ni = 0; ni < 4; ni++)
                acc[mi][ni] = __builtin_amdgcn_mfma_f32_16x16x32_bf16(a[mi], b[ni], acc[mi][ni], 0, 0, 0);
        __syncthreads();
    }
#undef G2_STAGE

#pragma unroll
    for (int mi = 0; mi < 4; mi++)
#pragma unroll
        for (int ni = 0; ni < 4; ni++)
#pragma unroll
            for (int r = 0; r < 4; r++) {
                int grow = row0 + wm * 64 + mi * 16 + quad * 4 + r;
                int gcol = n0 + wn * 64 + ni * 16 + m16;
                ycp[(size_t)grow * H + gcol] = acc[mi][ni][r];
            }
}

// ---------------- FALLBACK (small ws): round-2 fp32-weight GEMMs ----------------
__global__ __launch_bounds__(256) void k_gemm1f(const u16* __restrict__ xg,
                                                const float* __restrict__ w13,
                                                u16* __restrict__ act,
                                                const int* __restrict__ tile_e) {
    int id = blockIdx.x;
    int xcd = id & 7;
    int j = id >> 3;
    int tile = j % MAXTILES;
    int n0i = xcd * 8 + j / MAXTILES;
    int e = tile_e[tile];
    if (e < 0) return;
    __shared__ u16 As[2][BM * BK];
    __shared__ u16 Bs[2][2][64 * (BK + 8)];

    int tid = threadIdx.x;
    int lane = tid & 63, wave = tid >> 6;
    int quad = lane >> 4, m16 = lane & 15;
    int wm = wave >> 1, wn = wave & 1;
    int row0 = tile * BM;
    int n0 = n0i * 64;
    const float* wb1 = w13 + ((size_t)e * 2 * FFN + n0) * H;
    const float* wb3 = w13 + ((size_t)e * 2 * FFN + FFN + n0) * H;

    f32x4 accg[4][2], accu[4][2];
#pragma unroll
    for (int mi = 0; mi < 4; mi++)
#pragma unroll
        for (int ni = 0; ni < 2; ni++) { accg[mi][ni] = {0.f,0.f,0.f,0.f}; accu[mi][ni] = {0.f,0.f,0.f,0.f}; }

    float4 v1[2], v3[2];
#pragma unroll
    for (int i = 0; i < 2; i++) {
        int chunk = i * 256 + tid;
        GLD16(xg + (size_t)(row0 + (chunk >> 2)) * H + (chunk & 3) * 8, As[0] + chunk * 8);
    }
#pragma unroll
    for (int i = 0; i < 2; i++) {
        int idx = i * 256 + tid;
        v1[i] = *(const float4*)(wb1 + (size_t)(idx >> 3) * H + (idx & 7) * 4);
        v3[i] = *(const float4*)(wb3 + (size_t)(idx >> 3) * H + (idx & 7) * 4);
    }
#pragma unroll
    for (int i = 0; i < 2; i++) {
        int idx = i * 256 + tid;
        int r = idx >> 3, c4 = idx & 7;
        uint2 o1 = { cvt2(v1[i].x, v1[i].y), cvt2(v1[i].z, v1[i].w) };
        uint2 o3 = { cvt2(v3[i].x, v3[i].y), cvt2(v3[i].z, v3[i].w) };
        *(uint2*)&Bs[0][0][r * (BK + 8) + c4 * 4] = o1;
        *(uint2*)&Bs[0][1][r * (BK + 8) + c4 * 4] = o3;
    }
    __syncthreads();

    int aslot = quad ^ ((m16 >> 1) & 3);
    for (int it = 0; it < H / BK; ++it) {
        int cur = it & 1, nxt = cur ^ 1;
        int kk = (it + 1) * BK;
        bool pf = kk < H;
        if (pf) {
#pragma unroll
            for (int i = 0; i < 2; i++) {
                int chunk = i * 256 + tid;
                GLD16(xg + (size_t)(row0 + (chunk >> 2)) * H + kk + (chunk & 3) * 8, As[nxt] + chunk * 8);
            }
#pragma unroll
            for (int i = 0; i < 2; i++) {
                int idx = i * 256 + tid;
                v1[i] = *(const float4*)(wb1 + (size_t)(idx >> 3) * H + kk + (idx & 7) * 4);
                v3[i] = *(const float4*)(wb3 + (size_t)(idx >> 3) * H + kk + (idx & 7) * 4);
            }
        }
        bf16x8 a[4], bg[2], bu[2];
#pragma unroll
        for (int mi = 0; mi < 4; mi++)
            a[mi] = *(const bf16x8*)&As[cur][(wm * 64 + mi * 16 + m16) * BK + aslot * 8];
#pragma unroll
        for (int ni = 0; ni < 2; ni++) {
            bg[ni] = *(const bf16x8*)&Bs[cur][0][(wn * 32 + ni * 16 + m16) * (BK + 8) + quad * 8];
            bu[ni] = *(const bf16x8*)&Bs[cur][1][(wn * 32 + ni * 16 + m16) * (BK + 8) + quad * 8];
        }
#pragma unroll
        for (int mi = 0; mi < 4; mi++)
#pragma unroll
            for (int ni = 0; ni < 2; ni++) {
                accg[mi][ni] = __builtin_amdgcn_mfma_f32_16x16x32_bf16(a[mi], bg[ni], accg[mi][ni], 0, 0, 0);
                accu[mi][ni] = __builtin_amdgcn_mfma_f32_16x16x32_bf16(a[mi], bu[ni], accu[mi][ni], 0, 0, 0);
            }
        __builtin_amdgcn_sched_barrier(0);
        if (pf) {
#pragma unroll
            for (int i = 0; i < 2; i++) {
                int idx = i * 256 + tid;
                int r = idx >> 3, c4 = idx & 7;
                uint2 o1 = { cvt2(v1[i].x, v1[i].y), cvt2(v1[i].z, v1[i].w) };
                uint2 o3 = { cvt2(v3[i].x, v3[i].y), cvt2(v3[i].z, v3[i].w) };
                *(uint2*)&Bs[nxt][0][r * (BK + 8) + c4 * 4] = o1;
                *(uint2*)&Bs[nxt][1][r * (BK + 8) + c4 * 4] = o3;
            }
        }
        __syncthreads();
    }
#pragma unroll
    for (int mi = 0; mi < 4; mi++)
#pragma unroll
        for (int ni = 0; ni < 2; ni++) {
            int gcol = n0 + wn * 32 + ni * 16 + m16;
            int grow = row0 + wm * 64 + mi * 16 + quad * 4;
#pragma unroll
            for (int r = 0; r < 4; r++) {
                float g = accg[mi][ni][r], u = accu[mi][ni][r];
                float hv = g * (1.f / (1.f + __expf(-g))) * u;
                int f = ((quad * 4 + r) >> 1) & 3;
                act[(size_t)(grow + r) * FFN + (gcol ^ (f << 3))] = (u16)(cvt2(hv, hv) & 0xffff);
            }
        }
}

__global__ __launch_bounds__(256) void k_gemm2f(const u16* __restrict__ act,
                                                const float* __restrict__ w2,
                                                float* __restrict__ yc,
                                                const int* __restrict__ tile_e) {
    int id = blockIdx.x;
    int xcd = id & 7;
    int j = id >> 3;
    int tile = j % MAXTILES;
    int pz = xcd * 2 + j / MAXTILES;
    int e = tile_e[tile];
    if (e < 0) return;
    __shared__ u16 As[2][BM * BK];
    __shared__ u16 Bs[2][BM * (BK + 8)];

    int tid = threadIdx.x;
    int lane = tid & 63, wave = tid >> 6;
    int quad = lane >> 4, m16 = lane & 15;
    int wm = wave >> 1, wn = wave & 1;
    int row0 = tile * BM;
    int n0 = (pz >> 1) * 128;
    int z = pz & 1;
    int k0 = z * (FFN / 2);
    const float* wb = w2 + ((size_t)e * H + n0) * FFN;
    float* ycp = yc + (size_t)z * ROWCAP * H;

    f32x4 acc[4][4];
#pragma unroll
    for (int mi = 0; mi < 4; mi++)
#pragma unroll
        for (int ni = 0; ni < 4; ni++) acc[mi][ni] = {0.f,0.f,0.f,0.f};

    float4 v[4];
#pragma unroll
    for (int i = 0; i < 2; i++) {
        int chunk = i * 256 + tid;
        GLD16(act + (size_t)(row0 + (chunk >> 2)) * FFN + k0 + (chunk & 3) * 8, As[0] + chunk * 8);
    }
#pragma unroll
    for (int i = 0; i < 4; i++) {
        int idx = i * 256 + tid;
        v[i] = *(const float4*)(wb + (size_t)(idx >> 3) * FFN + k0 + (idx & 7) * 4);
    }
#pragma unroll
    for (int i = 0; i < 4; i++) {
        int idx = i * 256 + tid;
        int r = idx >> 3, c4 = idx & 7;
        uint2 o = { cvt2(v[i].x, v[i].y), cvt2(v[i].z, v[i].w) };
        *(uint2*)&Bs[0][r * (BK + 8) + c4 * 4] = o;
    }
    __syncthreads();

    int aslot = quad ^ ((m16 >> 1) & 3);
    const int NT = (FFN / 2) / BK;
    for (int it = 0; it < NT; ++it) {
        int cur = it & 1, nxt = cur ^ 1;
        int kk = k0 + (it + 1) * BK;
        bool pf = (it + 1) < NT;
        if (pf) {
#pragma unroll
            for (int i = 0; i < 2; i++) {
                int chunk = i * 256 + tid;
                GLD16(act + (size_t)(row0 + (chunk >> 2)) * FFN + kk + (chunk & 3) * 8, As[nxt] + chunk * 8);
            }
#pragma unroll
            for (int i = 0; i < 4; i++) {
                int idx = i * 256 + tid;
                v[i] = *(const float4*)(wb + (size_t)(idx >> 3) * FFN + kk + (idx & 7) * 4);
            }
        }
        bf16x8 a[4], b[4];
#pragma unroll
        for (int mi = 0; mi < 4; mi++)
            a[mi] = *(const bf16x8*)&As[cur][(wm * 64 + mi * 16 + m16) * BK + aslot * 8];
#pragma unroll
        for (int ni = 0; ni < 4; ni++)
            b[ni] = *(const bf16x8*)&Bs[cur][(wn * 64 + ni * 16 + m16) * (BK + 8) + quad * 8];
#pragma unroll
        for (int mi = 0; mi < 4; mi++)
#pragma unroll
            for (int ni = 0; ni < 4; ni++)
                acc[mi][ni] = __builtin_amdgcn_mfma_f32_16x16x32_bf16(a[mi], b[ni], acc[mi][ni], 0, 0, 0);
        __builtin_amdgcn_sched_barrier(0);
        if (pf) {
#pragma unroll
            for (int i = 0; i < 4; i++) {
                int idx = i * 256 + tid;
                int r = idx >> 3, c4 = idx & 7;
                uint2 o = { cvt2(v[i].x, v[i].y), cvt2(v[i].z, v[i].w) };
                *(uint2*)&Bs[nxt][r * (BK + 8) + c4 * 4] = o;
            }
        }
        __syncthreads();
    }
#pragma unroll
    for (int mi = 0; mi < 4; mi++)
#pragma unroll
        for (int ni = 0; ni < 4; ni++)
#pragma unroll
            for (int r = 0; r < 4; r++) {
                int grow = row0 + wm * 64 + mi * 16 + quad * 4 + r;
                int gcol = n0 + wn * 64 + ni * 16 + m16;
                ycp[(size_t)grow * H + gcol] = acc[mi][ni][r];
            }
}

// ---------------- kernel 7: combine (sums split-K partials) ----------------
__global__ void k_combine(const float4* __restrict__ yc4, const int* __restrict__ sel,
                          const int* __restrict__ posn, const int* __restrict__ base,
                          const float* __restrict__ wgt, float4* __restrict__ out4) {
    int t = blockIdx.x;
    int j = threadIdx.x;  // 256, H/4
    int r0 = base[sel[2 * t]] + posn[2 * t];
    int r1 = base[sel[2 * t + 1]] + posn[2 * t + 1];
    float w0 = wgt[2 * t], w1 = wgt[2 * t + 1];
    const size_t P = (size_t)ROWCAP * (H / 4);
    float4 a0 = yc4[(size_t)r0 * (H / 4) + j];
    float4 a1 = yc4[(size_t)r0 * (H / 4) + j + P];
    float4 b0 = yc4[(size_t)r1 * (H / 4) + j];
    float4 b1 = yc4[(size_t)r1 * (H / 4) + j + P];
    float4 o = { w0 * (a0.x + a1.x) + w1 * (b0.x + b1.x),
                 w0 * (a0.y + a1.y) + w1 * (b0.y + b1.y),
                 w0 * (a0.z + a1.z) + w1 * (b0.z + b1.z),
                 w0 * (a0.w + a1.w) + w1 * (b0.w + b1.w) };
    out4[(size_t)t * (H / 4) + j] = o;
}

extern "C" void kernel_launch(void* const* d_in, const int* in_sizes, int n_in,
                              void* d_out, int out_size, void* d_ws, size_t ws_size,
                              hipStream_t stream) {
    const float* x   = (const float*)d_in[0];
    const float* gw  = (const float*)d_in[1];
    const float* w13 = (const float*)d_in[2];
    const float* w2  = (const float*)d_in[3];
    float* out    = (float*)d_out;
    float* logits = out + (size_t)TOK * H;

    char* ws = (char*)d_ws;
    int*   counts = (int*)ws;
    int*   base   = (int*)(ws + 256);
    int*   tile_e = (int*)(ws + 512);
    int*   sel    = (int*)(ws + 1024);
    int*   posn   = (int*)(ws + 1024 + 4 * PAIRS);
    float* wgt    = (float*)(ws + 1024 + 8 * PAIRS);
    u16*   xg     = (u16*)(ws + 65536);
    u16*   act    = xg + (size_t)ROWCAP * H;

    const size_t W13B = (size_t)NE * 2 * FFN * H;   // u16 elems, 134.2MB
    const size_t W2B  = (size_t)NE * H * FFN;       // u16 elems, 67.1MB
    const size_t NEED = 65536 + (size_t)ROWCAP * H * 2 + (size_t)ROWCAP * FFN * 2
                      + W13B * 2 + W2B * 2;         // ~253.8MB (yc aliases w13b)

    k_init<<<1, 64, 0, stream>>>(counts);
    k_router<<<TOK / 4, 256, 0, stream>>>(x, gw, logits, counts, sel, posn, wgt);
    k_prefix<<<1, 64, 0, stream>>>(counts, base, tile_e);
    k_gather<<<PAIRS, 64, 0, stream>>>((const float4*)x, sel, posn, base, xg);

    if (ws_size >= NEED) {
        u16* w13b = act + (size_t)ROWCAP * FFN;
        u16* w2b  = w13b + W13B;
        float* yc = (float*)w13b;   // alias: w13b dead after gemm1, yc live from gemm2
        k_cvt13<<<NE * 2 * FFN / 4, 256, 0, stream>>>((const float4*)w13, w13b);
        k_cvt2<<<NE * H, 256, 0, stream>>>((const float4*)w2, w2b);
        k_gemm1b<<<dim3(MAXTILES * (FFN / 64)), 256, 0, stream>>>(xg, w13b, act, tile_e);
        k_gemm2b<<<dim3(MAXTILES * (H / 128) * 2), 256, 0, stream>>>(act, w2b, yc, tile_e);
        k_combine<<<TOK, 256, 0, stream>>>((const float4*)yc, sel, posn, base, wgt, (float4*)out);
    } else {
        float* yc = (float*)(act + (size_t)ROWCAP * FFN);
        k_gemm1f<<<dim3(MAXTILES * (FFN / 64)), 256, 0, stream>>>(xg, w13, act, tile_e);
        k_gemm2f<<<dim3(MAXTILES * (H / 128) * 2), 256, 0, stream>>>(act, w2, yc, tile_e);
        k_combine<<<TOK, 256, 0, stream>>>((const float4*)yc, sel, posn, base, wgt, (float4*)out);
    }
}